// Round 2
// baseline (294.573 us; speedup 1.0000x reference)
//
#include <hip/hip_runtime.h>

#define G3 32768          // 32^3 cells
#define NLOG2 12          // N = 4096 points per batch row
#define PPT 2             // points per thread

// One thread processes PPT points; for each point, all 3 plane reflections and
// 3 quaternion rotations are evaluated, each followed by the voxel-cell gather
// and masked squared-distance accumulation. Block covers a contiguous slab of
// points inside a single batch row -> gathers hit the same 393KB cp row (L2).
__global__ __launch_bounds__(256)
void symloss_kernel(const float* __restrict__ points,
                    const float* __restrict__ cp,
                    const float* __restrict__ voxel,
                    const float* __restrict__ plane,
                    const float* __restrict__ quat,
                    float* __restrict__ out,
                    int total, float invB)
{
    // ---- preload + precompute transform parameters (24 floats, L1-cached) ----
    float pnx[3], pny[3], pnz[3], pdd[3], pinv[3];
    float qw[3], qux[3], quy[3], quz[3];
#pragma unroll
    for (int i = 0; i < 3; ++i) {
        float nx = plane[4*i+0], ny = plane[4*i+1], nz = plane[4*i+2], dd = plane[4*i+3];
        pnx[i] = nx; pny[i] = ny; pnz[i] = nz; pdd[i] = dd;
        pinv[i] = 1.0f / (nx*nx + ny*ny + nz*nz);

        float w  = quat[4*i+0], ux = quat[4*i+1], uy = quat[4*i+2], uz = quat[4*i+3];
        float rn = 1.0f / sqrtf(w*w + ux*ux + uy*uy + uz*uz);
        qw[i] = w*rn; qux[i] = ux*rn; quy[i] = uy*rn; quz[i] = uz*rn;
    }

    const float gmin = -0.484375f;   // -0.5 + 0.5/32, exact in f32

    float accR = 0.0f, accQ = 0.0f;

    int base = blockIdx.x * (blockDim.x * PPT);
#pragma unroll
    for (int i = 0; i < PPT; ++i) {
        int g = base + i * blockDim.x + threadIdx.x;
        if (g < total) {
            int b = g >> NLOG2;                       // batch index (N = 4096)
            const float* __restrict__ cpb  = cp    + (size_t)b * (G3 * 3);
            const float* __restrict__ voxb = voxel + (size_t)b * G3;

            float px = points[3*g+0];
            float py = points[3*g+1];
            float pz = points[3*g+2];

#pragma unroll
            for (int t = 0; t < 3; ++t) {
                // ---------- plane reflection ----------
                float dist = (px*pnx[t] + py*pny[t] + pz*pnz[t] + pdd[t]) * pinv[t];
                float rx = px - 2.0f * dist * pnx[t];
                float ry = py - 2.0f * dist * pny[t];
                float rz = pz - 2.0f * dist * pnz[t];
                {
                    float fx = rintf(fminf(fmaxf((rx - gmin) * 32.0f, 0.0f), 31.0f));
                    float fy = rintf(fminf(fmaxf((ry - gmin) * 32.0f, 0.0f), 31.0f));
                    float fz = rintf(fminf(fmaxf((rz - gmin) * 32.0f, 0.0f), 31.0f));
                    int idx = (int)(fx * 1024.0f + fy * 32.0f + fz);
                    float m  = 1.0f - voxb[idx];
                    float dx = (rx - cpb[3*idx+0]) * m;
                    float dy = (ry - cpb[3*idx+1]) * m;
                    float dz = (rz - cpb[3*idx+2]) * m;
                    accR += dx*dx + dy*dy + dz*dz;
                }

                // ---------- quaternion rotation ----------
                float tx = 2.0f * (quy[t]*pz - quz[t]*py);
                float ty = 2.0f * (quz[t]*px - qux[t]*pz);
                float tz = 2.0f * (qux[t]*py - quy[t]*px);
                float ox = px + qw[t]*tx + (quy[t]*tz - quz[t]*ty);
                float oy = py + qw[t]*ty + (quz[t]*tx - qux[t]*tz);
                float oz = pz + qw[t]*tz + (qux[t]*ty - quy[t]*tx);
                {
                    float fx = rintf(fminf(fmaxf((ox - gmin) * 32.0f, 0.0f), 31.0f));
                    float fy = rintf(fminf(fmaxf((oy - gmin) * 32.0f, 0.0f), 31.0f));
                    float fz = rintf(fminf(fmaxf((oz - gmin) * 32.0f, 0.0f), 31.0f));
                    int idx = (int)(fx * 1024.0f + fy * 32.0f + fz);
                    float m  = 1.0f - voxb[idx];
                    float dx = (ox - cpb[3*idx+0]) * m;
                    float dy = (oy - cpb[3*idx+1]) * m;
                    float dz = (oz - cpb[3*idx+2]) * m;
                    accQ += dx*dx + dy*dy + dz*dz;
                }
            }
        }
    }

    // ---- block reduction: wave shuffle, then LDS across the 4 waves ----
#pragma unroll
    for (int off = 32; off > 0; off >>= 1) {
        accR += __shfl_down(accR, off, 64);
        accQ += __shfl_down(accQ, off, 64);
    }
    __shared__ float sR[4], sQ[4];
    int wave = threadIdx.x >> 6;
    int lane = threadIdx.x & 63;
    if (lane == 0) { sR[wave] = accR; sQ[wave] = accQ; }
    __syncthreads();
    if (threadIdx.x == 0) {
        float r = sR[0] + sR[1] + sR[2] + sR[3];
        float q = sQ[0] + sQ[1] + sQ[2] + sQ[3];
        atomicAdd(&out[0], r * invB);   // mean over batch applied here
        atomicAdd(&out[1], q * invB);
    }
}

extern "C" void kernel_launch(void* const* d_in, const int* in_sizes, int n_in,
                              void* d_out, int out_size, void* d_ws, size_t ws_size,
                              hipStream_t stream)
{
    const float* points = (const float*)d_in[0];
    const float* cp     = (const float*)d_in[1];
    const float* voxel  = (const float*)d_in[2];
    const float* plane  = (const float*)d_in[3];
    const float* quat   = (const float*)d_in[4];
    float* out = (float*)d_out;

    int total = in_sizes[0] / 3;          // B * N = 1,048,576 points
    int B     = in_sizes[2] / G3;         // 256
    float invB = 1.0f / (float)B;

    hipMemsetAsync(out, 0, (size_t)out_size * sizeof(float), stream);

    int threads = 256;
    int blocks  = (total + threads * PPT - 1) / (threads * PPT);  // 2048
    symloss_kernel<<<blocks, threads, 0, stream>>>(points, cp, voxel, plane, quat,
                                                   out, total, invB);
}

// Round 3
// 214.016 us; speedup vs baseline: 1.3764x; 1.3764x over previous
//
#include <hip/hip_runtime.h>

#define G3 32768          // 32^3 cells per batch row
#define SLABS 4           // slabs per row
#define SLAB_CELLS 8192   // cells per slab -> 128 KB of float4 in LDS
#define TPB 1024          // threads per block (16 waves)

// Grid = B rows x 4 slabs. Each block stages its slab of {cp.xyz, 1-voxel}
// into LDS (sequential, read-once, nontemporal), then streams the row's
// points, evaluates all 6 symmetry transforms in-register, and accumulates
// the masked squared distance for transforms whose cell lands in this slab.
// Random global gathers are replaced by predicated LDS reads.
__global__ __launch_bounds__(TPB)
void symloss_slab_kernel(const float* __restrict__ points,
                         const float* __restrict__ cp,
                         const float* __restrict__ voxel,
                         const float* __restrict__ plane,
                         const float* __restrict__ quat,
                         float* __restrict__ out,
                         int N, float invB)
{
    __shared__ float4 slab[SLAB_CELLS];          // 128 KB
    __shared__ float sR[TPB / 64], sQ[TPB / 64]; // cross-wave reduction

    const int row  = blockIdx.x >> 2;            // batch row
    const int base = (blockIdx.x & 3) * SLAB_CELLS;

    const float* __restrict__ cpb  = cp     + (size_t)row * (G3 * 3);
    const float* __restrict__ voxb = voxel  + (size_t)row * G3;
    const float* __restrict__ ptb  = points + (size_t)row * (size_t)N * 3;

    // ---- transform parameters (uniform, L1/scalar-cached) ----
    float pnx[3], pny[3], pnz[3], pdd[3], pinv[3];
    float qw[3], qux[3], quy[3], quz[3];
#pragma unroll
    for (int i = 0; i < 3; ++i) {
        float nx = plane[4*i+0], ny = plane[4*i+1], nz = plane[4*i+2], dd = plane[4*i+3];
        pnx[i] = nx; pny[i] = ny; pnz[i] = nz; pdd[i] = dd;
        pinv[i] = 1.0f / (nx*nx + ny*ny + nz*nz);

        float w  = quat[4*i+0], ux = quat[4*i+1], uy = quat[4*i+2], uz = quat[4*i+3];
        float rn = 1.0f / sqrtf(w*w + ux*ux + uy*uy + uz*uz);
        qw[i] = w*rn; qux[i] = ux*rn; quy[i] = uy*rn; quz[i] = uz*rn;
    }

    // ---- stage slab: sequential read-once, packed {cp.xyz, mask} ----
#pragma unroll
    for (int c = threadIdx.x; c < SLAB_CELLS; c += TPB) {
        int g = base + c;
        float4 v;
        v.x = __builtin_nontemporal_load(&cpb[3*g+0]);
        v.y = __builtin_nontemporal_load(&cpb[3*g+1]);
        v.z = __builtin_nontemporal_load(&cpb[3*g+2]);
        v.w = 1.0f - __builtin_nontemporal_load(&voxb[g]);
        slab[c] = v;
    }
    __syncthreads();

    const float gmin = -0.484375f;   // -0.5 + 0.5/32, exact in f32

    float accR = 0.0f, accQ = 0.0f;

    // ---- stream points, 6 transforms each, predicated LDS gather ----
    for (int p = threadIdx.x; p < N; p += TPB) {
        float px = ptb[3*p+0];
        float py = ptb[3*p+1];
        float pz = ptb[3*p+2];

#pragma unroll
        for (int t = 0; t < 3; ++t) {
            // ---------- plane reflection ----------
            float dist = (px*pnx[t] + py*pny[t] + pz*pnz[t] + pdd[t]) * pinv[t];
            float rx = px - 2.0f * dist * pnx[t];
            float ry = py - 2.0f * dist * pny[t];
            float rz = pz - 2.0f * dist * pnz[t];
            {
                float fx = rintf(fminf(fmaxf((rx - gmin) * 32.0f, 0.0f), 31.0f));
                float fy = rintf(fminf(fmaxf((ry - gmin) * 32.0f, 0.0f), 31.0f));
                float fz = rintf(fminf(fmaxf((rz - gmin) * 32.0f, 0.0f), 31.0f));
                int local = (int)(fx * 1024.0f + fy * 32.0f + fz) - base;
                if ((unsigned)local < SLAB_CELLS) {
                    float4 c4 = slab[local];
                    float dx = (rx - c4.x) * c4.w;
                    float dy = (ry - c4.y) * c4.w;
                    float dz = (rz - c4.z) * c4.w;
                    accR += dx*dx + dy*dy + dz*dz;
                }
            }

            // ---------- quaternion rotation ----------
            float tx = 2.0f * (quy[t]*pz - quz[t]*py);
            float ty = 2.0f * (quz[t]*px - qux[t]*pz);
            float tz = 2.0f * (qux[t]*py - quy[t]*px);
            float ox = px + qw[t]*tx + (quy[t]*tz - quz[t]*ty);
            float oy = py + qw[t]*ty + (quz[t]*tx - qux[t]*tz);
            float oz = pz + qw[t]*tz + (qux[t]*ty - quy[t]*tx);
            {
                float fx = rintf(fminf(fmaxf((ox - gmin) * 32.0f, 0.0f), 31.0f));
                float fy = rintf(fminf(fmaxf((oy - gmin) * 32.0f, 0.0f), 31.0f));
                float fz = rintf(fminf(fmaxf((oz - gmin) * 32.0f, 0.0f), 31.0f));
                int local = (int)(fx * 1024.0f + fy * 32.0f + fz) - base;
                if ((unsigned)local < SLAB_CELLS) {
                    float4 c4 = slab[local];
                    float dx = (ox - c4.x) * c4.w;
                    float dy = (oy - c4.y) * c4.w;
                    float dz = (oz - c4.z) * c4.w;
                    accQ += dx*dx + dy*dy + dz*dz;
                }
            }
        }
    }

    // ---- reduction: wave shuffle, then LDS across the 16 waves ----
#pragma unroll
    for (int off = 32; off > 0; off >>= 1) {
        accR += __shfl_down(accR, off, 64);
        accQ += __shfl_down(accQ, off, 64);
    }
    int wave = threadIdx.x >> 6;
    int lane = threadIdx.x & 63;
    if (lane == 0) { sR[wave] = accR; sQ[wave] = accQ; }
    __syncthreads();
    if (threadIdx.x == 0) {
        float r = 0.0f, q = 0.0f;
#pragma unroll
        for (int w = 0; w < TPB / 64; ++w) { r += sR[w]; q += sQ[w]; }
        atomicAdd(&out[0], r * invB);   // mean over batch applied here
        atomicAdd(&out[1], q * invB);
    }
}

extern "C" void kernel_launch(void* const* d_in, const int* in_sizes, int n_in,
                              void* d_out, int out_size, void* d_ws, size_t ws_size,
                              hipStream_t stream)
{
    const float* points = (const float*)d_in[0];
    const float* cp     = (const float*)d_in[1];
    const float* voxel  = (const float*)d_in[2];
    const float* plane  = (const float*)d_in[3];
    const float* quat   = (const float*)d_in[4];
    float* out = (float*)d_out;

    int B = in_sizes[2] / G3;                 // 256
    int N = (in_sizes[0] / 3) / B;            // 4096
    float invB = 1.0f / (float)B;

    hipMemsetAsync(out, 0, (size_t)out_size * sizeof(float), stream);

    symloss_slab_kernel<<<B * SLABS, TPB, 0, stream>>>(points, cp, voxel, plane, quat,
                                                       out, N, invB);
}

// Round 5
// 207.127 us; speedup vs baseline: 1.4222x; 1.0333x over previous
//
#include <hip/hip_runtime.h>
#include <hip/hip_fp16.h>

#define G3 32768          // 32^3 cells per batch row
#define SLABS 2           // slabs per row
#define SLAB_CELLS 16384  // cells per slab -> 128 KB of uint2 (fp16x4) in LDS
#define TPB 1024          // threads per block (16 waves)

typedef float f32x4 __attribute__((ext_vector_type(4)));   // clang vector: OK for nontemporal builtins

static __device__ __forceinline__ unsigned pack2h(float a, float b) {
    unsigned short ua = __half_as_ushort(__float2half(a));
    unsigned short ub = __half_as_ushort(__float2half(b));
    return (unsigned)ua | ((unsigned)ub << 16);
}
static __device__ __forceinline__ float lo2f(unsigned u) {
    return __half2float(__ushort_as_half((unsigned short)(u & 0xffffu)));
}
static __device__ __forceinline__ float hi2f(unsigned u) {
    return __half2float(__ushort_as_half((unsigned short)(u >> 16)));
}

// Each transform result: clip/round to cell, predicated LDS gather, masked sqdist.
#define PROCESS(PX, PY, PZ, ACCR_EXPR, ACCQ_EXPR)                                   \
    do {                                                                            \
        _Pragma("unroll")                                                           \
        for (int t = 0; t < 3; ++t) {                                               \
            /* ---------- plane reflection ---------- */                            \
            float dist = ((PX)*pnx[t] + (PY)*pny[t] + (PZ)*pnz[t] + pdd[t]) * pinv[t]; \
            float rx = (PX) - 2.0f * dist * pnx[t];                                 \
            float ry = (PY) - 2.0f * dist * pny[t];                                 \
            float rz = (PZ) - 2.0f * dist * pnz[t];                                 \
            {                                                                       \
                float fx = rintf(fminf(fmaxf((rx - gmin) * 32.0f, 0.0f), 31.0f));   \
                float fy = rintf(fminf(fmaxf((ry - gmin) * 32.0f, 0.0f), 31.0f));   \
                float fz = rintf(fminf(fmaxf((rz - gmin) * 32.0f, 0.0f), 31.0f));   \
                int local = (int)(fx * 1024.0f + fy * 32.0f + fz) - base;           \
                if ((unsigned)local < SLAB_CELLS) {                                 \
                    uint2 u = slab[local];                                          \
                    float m  = hi2f(u.y);                                           \
                    float dx = (rx - lo2f(u.x)) * m;                                \
                    float dy = (ry - hi2f(u.x)) * m;                                \
                    float dz = (rz - lo2f(u.y)) * m;                                \
                    ACCR_EXPR += dx*dx + dy*dy + dz*dz;                             \
                }                                                                   \
            }                                                                       \
            /* ---------- quaternion rotation ---------- */                         \
            float tx = 2.0f * (quy[t]*(PZ) - quz[t]*(PY));                          \
            float ty = 2.0f * (quz[t]*(PX) - qux[t]*(PZ));                          \
            float tz = 2.0f * (qux[t]*(PY) - quy[t]*(PX));                          \
            float ox = (PX) + qw[t]*tx + (quy[t]*tz - quz[t]*ty);                   \
            float oy = (PY) + qw[t]*ty + (quz[t]*tx - qux[t]*tz);                   \
            float oz = (PZ) + qw[t]*tz + (qux[t]*ty - quy[t]*tx);                   \
            {                                                                       \
                float fx = rintf(fminf(fmaxf((ox - gmin) * 32.0f, 0.0f), 31.0f));   \
                float fy = rintf(fminf(fmaxf((oy - gmin) * 32.0f, 0.0f), 31.0f));   \
                float fz = rintf(fminf(fmaxf((oz - gmin) * 32.0f, 0.0f), 31.0f));   \
                int local = (int)(fx * 1024.0f + fy * 32.0f + fz) - base;           \
                if ((unsigned)local < SLAB_CELLS) {                                 \
                    uint2 u = slab[local];                                          \
                    float m  = hi2f(u.y);                                           \
                    float dx = (ox - lo2f(u.x)) * m;                                \
                    float dy = (oy - hi2f(u.x)) * m;                                \
                    float dz = (oz - lo2f(u.y)) * m;                                \
                    ACCQ_EXPR += dx*dx + dy*dy + dz*dz;                             \
                }                                                                   \
            }                                                                       \
        }                                                                           \
    } while (0)

// Grid = B rows x 2 slabs. Stage slab as packed fp16 {cp.xyz, 1-voxel} (8 B/cell)
// via vectorized float4 reads; points pre-loaded into registers so the compute
// phase is global-memory-free. Random global gathers -> predicated LDS b64 reads.
__global__ __launch_bounds__(TPB)
void symloss_slab_kernel(const float* __restrict__ points,
                         const float* __restrict__ cp,
                         const float* __restrict__ voxel,
                         const float* __restrict__ plane,
                         const float* __restrict__ quat,
                         float* __restrict__ out,
                         int N, float invB)
{
    __shared__ uint2 slab[SLAB_CELLS];           // 128 KB
    __shared__ float sR[TPB / 64], sQ[TPB / 64];

    const int row  = blockIdx.x >> 1;
    const int base = (blockIdx.x & 1) * SLAB_CELLS;

    const float* __restrict__ cpb  = cp     + (size_t)row * (G3 * 3) + (size_t)base * 3;
    const float* __restrict__ voxb = voxel  + (size_t)row * G3 + base;
    const float* __restrict__ ptb  = points + (size_t)row * (size_t)N * 3;

    // ---- issue this thread's point loads FIRST (overlap with staging) ----
    const float4* __restrict__ pt4 = reinterpret_cast<const float4*>(ptb);
    const int ngrp = N >> 2;                     // point-groups of 4
    float4 q0, q1, q2;
    const bool havePts = (int)threadIdx.x < ngrp;
    if (havePts) {
        q0 = pt4[3 * threadIdx.x + 0];
        q1 = pt4[3 * threadIdx.x + 1];
        q2 = pt4[3 * threadIdx.x + 2];
    }

    // ---- transform parameters (uniform, cached) ----
    float pnx[3], pny[3], pnz[3], pdd[3], pinv[3];
    float qw[3], qux[3], quy[3], quz[3];
#pragma unroll
    for (int i = 0; i < 3; ++i) {
        float nx = plane[4*i+0], ny = plane[4*i+1], nz = plane[4*i+2], dd = plane[4*i+3];
        pnx[i] = nx; pny[i] = ny; pnz[i] = nz; pdd[i] = dd;
        pinv[i] = 1.0f / (nx*nx + ny*ny + nz*nz);

        float w  = quat[4*i+0], ux = quat[4*i+1], uy = quat[4*i+2], uz = quat[4*i+3];
        float rn = 1.0f / sqrtf(w*w + ux*ux + uy*uy + uz*uz);
        qw[i] = w*rn; qux[i] = ux*rn; quy[i] = uy*rn; quz[i] = uz*rn;
    }

    // ---- stage slab: vectorized float4 reads, fp16-packed LDS writes ----
    const f32x4* __restrict__ cp4 = reinterpret_cast<const f32x4*>(cpb);
    const f32x4* __restrict__ vx4 = reinterpret_cast<const f32x4*>(voxb);
#pragma unroll 2
    for (int gI = threadIdx.x; gI < SLAB_CELLS / 4; gI += TPB) {
        f32x4 v0 = __builtin_nontemporal_load(&cp4[3*gI+0]);
        f32x4 v1 = __builtin_nontemporal_load(&cp4[3*gI+1]);
        f32x4 v2 = __builtin_nontemporal_load(&cp4[3*gI+2]);
        f32x4 w  = __builtin_nontemporal_load(&vx4[gI]);
        uint2 c0; c0.x = pack2h(v0.x, v0.y); c0.y = pack2h(v0.z, 1.0f - w.x);
        uint2 c1; c1.x = pack2h(v0.w, v1.x); c1.y = pack2h(v1.y, 1.0f - w.y);
        uint2 c2; c2.x = pack2h(v1.z, v1.w); c2.y = pack2h(v2.x, 1.0f - w.z);
        uint2 c3; c3.x = pack2h(v2.y, v2.z); c3.y = pack2h(v2.w, 1.0f - w.w);
        slab[4*gI+0] = c0; slab[4*gI+1] = c1;
        slab[4*gI+2] = c2; slab[4*gI+3] = c3;
    }
    __syncthreads();

    const float gmin = -0.484375f;   // -0.5 + 0.5/32, exact in f32
    float accR = 0.0f, accQ = 0.0f;

    // ---- compute: 4 register-resident points x 6 transforms ----
    if (havePts) {
        PROCESS(q0.x, q0.y, q0.z, accR, accQ);
        PROCESS(q0.w, q1.x, q1.y, accR, accQ);
        PROCESS(q1.z, q1.w, q2.x, accR, accQ);
        PROCESS(q2.y, q2.z, q2.w, accR, accQ);
    }
    // generic tail (only taken if N > 4*TPB)
    for (int g4 = threadIdx.x + TPB; g4 < ngrp; g4 += TPB) {
        float4 a0 = pt4[3*g4+0], a1 = pt4[3*g4+1], a2 = pt4[3*g4+2];
        PROCESS(a0.x, a0.y, a0.z, accR, accQ);
        PROCESS(a0.w, a1.x, a1.y, accR, accQ);
        PROCESS(a1.z, a1.w, a2.x, accR, accQ);
        PROCESS(a2.y, a2.z, a2.w, accR, accQ);
    }

    // ---- reduction: wave shuffle, then LDS across the 16 waves ----
#pragma unroll
    for (int off = 32; off > 0; off >>= 1) {
        accR += __shfl_down(accR, off, 64);
        accQ += __shfl_down(accQ, off, 64);
    }
    int wave = threadIdx.x >> 6;
    int lane = threadIdx.x & 63;
    if (lane == 0) { sR[wave] = accR; sQ[wave] = accQ; }
    __syncthreads();
    if (threadIdx.x == 0) {
        float r = 0.0f, q = 0.0f;
#pragma unroll
        for (int w = 0; w < TPB / 64; ++w) { r += sR[w]; q += sQ[w]; }
        atomicAdd(&out[0], r * invB);   // mean over batch applied here
        atomicAdd(&out[1], q * invB);
    }
}

extern "C" void kernel_launch(void* const* d_in, const int* in_sizes, int n_in,
                              void* d_out, int out_size, void* d_ws, size_t ws_size,
                              hipStream_t stream)
{
    const float* points = (const float*)d_in[0];
    const float* cp     = (const float*)d_in[1];
    const float* voxel  = (const float*)d_in[2];
    const float* plane  = (const float*)d_in[3];
    const float* quat   = (const float*)d_in[4];
    float* out = (float*)d_out;

    int B = in_sizes[2] / G3;                 // 256
    int N = (in_sizes[0] / 3) / B;            // 4096
    float invB = 1.0f / (float)B;

    (void)hipMemsetAsync(out, 0, (size_t)out_size * sizeof(float), stream);

    symloss_slab_kernel<<<B * SLABS, TPB, 0, stream>>>(points, cp, voxel, plane, quat,
                                                       out, N, invB);
}